// Round 1
// baseline (3259.460 us; speedup 1.0000x reference)
//
#include <hip/hip_runtime.h>
#include <math.h>

#define NN 50000
#define NE 800000
#define F_IN 512
#define F_MID 256
#define F_OUT 40
#define LN_EPS 1e-5f

// ---------------- degree ----------------
__global__ void k_deg_init(float* __restrict__ deg) {
    int i = blockIdx.x * blockDim.x + threadIdx.x;
    if (i < NN) deg[i] = 1.0f;  // self loop
}

__global__ void k_deg_count(const int* __restrict__ ei, float* __restrict__ deg) {
    int e = blockIdx.x * blockDim.x + threadIdx.x;
    if (e < NE) atomicAdd(&deg[ei[NE + e]], 1.0f);
}

__global__ void k_dinv(float* __restrict__ deg) {
    int i = blockIdx.x * blockDim.x + threadIdx.x;
    if (i < NN) deg[i] = rsqrtf(deg[i]);
}

// ---------------- GEMM1: h1p = (X @ W1) * dinv[row] ----------------
// X [NN,512], W1 [512,256], out [NN,256]. 64x64 tile, BK=32, 4x4 per thread.
__global__ __launch_bounds__(256) void k_gemm1(const float* __restrict__ X,
                                               const float* __restrict__ W,
                                               const float* __restrict__ dinv,
                                               float* __restrict__ H) {
    __shared__ float xs[64][33];
    __shared__ float ws[32][64];
    int t = threadIdx.x;
    int r0 = blockIdx.x * 64;
    int c0 = blockIdx.y * 64;
    int n0 = (t & 15) * 4;
    int f0 = (t >> 4) * 4;
    float acc[4][4] = {};

    for (int kk = 0; kk < F_IN; kk += 32) {
        // load X tile: 64 rows x 32 k
        {
            int r = t >> 3;            // 0..31
            int kc = (t & 7) * 4;      // 0..28
#pragma unroll
            for (int h = 0; h < 2; ++h) {
                int row = r + h * 32;
                int gr = r0 + row;
                float4 v = make_float4(0.f, 0.f, 0.f, 0.f);
                if (gr < NN) v = *(const float4*)&X[(size_t)gr * F_IN + kk + kc];
                xs[row][kc + 0] = v.x; xs[row][kc + 1] = v.y;
                xs[row][kc + 2] = v.z; xs[row][kc + 3] = v.w;
            }
        }
        // load W tile: 32 k x 64 cols
        {
#pragma unroll
            for (int h = 0; h < 2; ++h) {
                int i = t + h * 256;
                int k = i >> 4;            // 0..31
                int c = (i & 15) * 4;      // 0..60
                *(float4*)&ws[k][c] = *(const float4*)&W[(size_t)(kk + k) * F_MID + c0 + c];
            }
        }
        __syncthreads();
#pragma unroll
        for (int k = 0; k < 32; ++k) {
            float4 wv = *(float4*)&ws[k][f0];
            float a0 = xs[n0 + 0][k];
            float a1 = xs[n0 + 1][k];
            float a2 = xs[n0 + 2][k];
            float a3 = xs[n0 + 3][k];
            acc[0][0] += a0 * wv.x; acc[0][1] += a0 * wv.y; acc[0][2] += a0 * wv.z; acc[0][3] += a0 * wv.w;
            acc[1][0] += a1 * wv.x; acc[1][1] += a1 * wv.y; acc[1][2] += a1 * wv.z; acc[1][3] += a1 * wv.w;
            acc[2][0] += a2 * wv.x; acc[2][1] += a2 * wv.y; acc[2][2] += a2 * wv.z; acc[2][3] += a2 * wv.w;
            acc[3][0] += a3 * wv.x; acc[3][1] += a3 * wv.y; acc[3][2] += a3 * wv.z; acc[3][3] += a3 * wv.w;
        }
        __syncthreads();
    }
#pragma unroll
    for (int i = 0; i < 4; ++i) {
        int row = r0 + n0 + i;
        if (row >= NN) continue;
        float s = dinv[row];
        float4 o = make_float4(acc[i][0] * s, acc[i][1] * s, acc[i][2] * s, acc[i][3] * s);
        *(float4*)&H[(size_t)row * F_MID + c0 + f0] = o;
    }
}

// ---------------- scatter layer 1: agg1[dst] += h1p[src] (wave per edge) ----------------
__global__ void k_scatter1(const int* __restrict__ ei, const float* __restrict__ H,
                           float* __restrict__ A) {
    int gid = blockIdx.x * blockDim.x + threadIdx.x;
    int e = gid >> 6;
    int lane = gid & 63;
    if (e >= NE) return;
    int src = ei[e];
    int dst = ei[NE + e];
    float4 v = *(const float4*)&H[(size_t)src * F_MID + lane * 4];
    float* a = &A[(size_t)dst * F_MID + lane * 4];
    atomicAdd(a + 0, v.x);
    atomicAdd(a + 1, v.y);
    atomicAdd(a + 2, v.z);
    atomicAdd(a + 3, v.w);
}

// ---------------- fused: v = dinv*(agg1 + h1p) + b1 -> LN(256) -> ELU -> h1p ----------------
__global__ __launch_bounds__(256) void k_ln1(const float* __restrict__ A, float* __restrict__ H,
                                             const float* __restrict__ dinv,
                                             const float* __restrict__ b,
                                             const float* __restrict__ g,
                                             const float* __restrict__ be) {
    int i = blockIdx.x;
    int t = threadIdx.x;
    float s = dinv[i];
    size_t off = (size_t)i * F_MID + t;
    float v = s * (A[off] + H[off]) + b[t];

    __shared__ float red[4][2];
    float sum = v, sq = v * v;
#pragma unroll
    for (int o = 32; o; o >>= 1) {
        sum += __shfl_down(sum, o, 64);
        sq  += __shfl_down(sq, o, 64);
    }
    int wid = t >> 6;
    if ((t & 63) == 0) { red[wid][0] = sum; red[wid][1] = sq; }
    __syncthreads();
    if (t == 0) {
        float S = 0.f, Q = 0.f;
#pragma unroll
        for (int w = 0; w < 4; ++w) { S += red[w][0]; Q += red[w][1]; }
        red[0][0] = S; red[0][1] = Q;
    }
    __syncthreads();
    float mu = red[0][0] * (1.0f / F_MID);
    float var = red[0][1] * (1.0f / F_MID) - mu * mu;
    float y = (v - mu) * rsqrtf(var + LN_EPS) * g[t] + be[t];
    H[off] = y > 0.f ? y : expm1f(y);
}

// ---------------- GEMM2: h2p = (a1 @ W2) * dinv  [NN,40] ----------------
__global__ __launch_bounds__(320) void k_gemm2(const float* __restrict__ Hin,
                                               const float* __restrict__ W,
                                               const float* __restrict__ dinv,
                                               float* __restrict__ H2) {
    __shared__ float wls[F_MID * F_OUT];    // 40 KB
    __shared__ float as[8][F_MID + 4];      // padded rows (8.3 KB)
    int t = threadIdx.x;
    int r0 = blockIdx.x * 8;
    // load W2 (10240 floats = 2560 float4, 320 threads -> 8 each)
#pragma unroll
    for (int j = 0; j < 8; ++j) {
        int idx = (t + j * 320) * 4;
        *(float4*)&wls[idx] = *(const float4*)&W[idx];
    }
    // load a-tile: 512 float4
    for (int j = t; j < 512; j += 320) {
        int n = j >> 6;
        int col = (j & 63) * 4;
        int gr = r0 + n;
        float4 v = make_float4(0.f, 0.f, 0.f, 0.f);
        if (gr < NN) v = *(const float4*)&Hin[(size_t)gr * F_MID + col];
        *(float4*)&as[n][col] = v;
    }
    __syncthreads();
    int n = t / F_OUT;   // 0..7 exactly (320 = 8*40)
    int f = t % F_OUT;
    float acc = 0.f;
#pragma unroll 4
    for (int k = 0; k < F_MID; ++k) acc += as[n][k] * wls[k * F_OUT + f];
    int gr = r0 + n;
    if (gr < NN) H2[(size_t)gr * F_OUT + f] = acc * dinv[gr];
}

// ---------------- scatter layer 2 ----------------
__global__ void k_scatter2(const int* __restrict__ ei, const float* __restrict__ H2,
                           float* __restrict__ A2) {
    int gid = blockIdx.x * blockDim.x + threadIdx.x;
    int e = gid >> 6;
    int lane = gid & 63;
    if (e >= NE || lane >= F_OUT) return;
    int src = ei[e];
    int dst = ei[NE + e];
    atomicAdd(&A2[(size_t)dst * F_OUT + lane], H2[(size_t)src * F_OUT + lane]);
}

// ---------------- final: LN(40) -> ELU -> log_softmax (wave per node) ----------------
__global__ __launch_bounds__(256) void k_final(const float* __restrict__ A2,
                                               const float* __restrict__ H2,
                                               const float* __restrict__ dinv,
                                               const float* __restrict__ b,
                                               const float* __restrict__ g,
                                               const float* __restrict__ be,
                                               float* __restrict__ out) {
    int gid = blockIdx.x * blockDim.x + threadIdx.x;
    int i = gid >> 6;
    int lane = gid & 63;
    if (i >= NN) return;
    bool act = lane < F_OUT;
    size_t off = (size_t)i * F_OUT + lane;
    float v = 0.f;
    if (act) v = dinv[i] * (A2[off] + H2[off]) + b[lane];
    float sum = act ? v : 0.f;
    float sq = act ? v * v : 0.f;
#pragma unroll
    for (int o = 32; o; o >>= 1) {
        sum += __shfl_xor(sum, o, 64);
        sq  += __shfl_xor(sq, o, 64);
    }
    float mu = sum * (1.0f / F_OUT);
    float var = sq * (1.0f / F_OUT) - mu * mu;
    float rs = rsqrtf(var + LN_EPS);
    float y = act ? ((v - mu) * rs * g[lane] + be[lane]) : 0.f;
    float el = y > 0.f ? y : expm1f(y);
    float m = act ? el : -INFINITY;
#pragma unroll
    for (int o = 32; o; o >>= 1) m = fmaxf(m, __shfl_xor(m, o, 64));
    float ex = act ? expf(el - m) : 0.f;
    float se = ex;
#pragma unroll
    for (int o = 32; o; o >>= 1) se += __shfl_xor(se, o, 64);
    if (act) out[off] = el - m - logf(se);
}

extern "C" void kernel_launch(void* const* d_in, const int* in_sizes, int n_in,
                              void* d_out, int out_size, void* d_ws, size_t ws_size,
                              hipStream_t stream) {
    const float* x   = (const float*)d_in[0];
    const int*   ei  = (const int*)d_in[1];
    const float* W1  = (const float*)d_in[2];
    const float* b1  = (const float*)d_in[3];
    const float* g1  = (const float*)d_in[4];
    const float* be1 = (const float*)d_in[5];
    const float* W2  = (const float*)d_in[6];
    const float* b2  = (const float*)d_in[7];
    const float* g2  = (const float*)d_in[8];
    const float* be2 = (const float*)d_in[9];
    float* out = (float*)d_out;

    float* ws   = (float*)d_ws;
    float* dinv = ws;                       // NN
    float* h1p  = ws + 51200;               // NN*256
    float* agg1 = h1p + (size_t)NN * F_MID; // NN*256
    float* h2p  = agg1 + (size_t)NN * F_MID;// NN*40
    float* agg2 = h2p + (size_t)NN * F_OUT; // NN*40

    hipMemsetAsync(agg1, 0, (size_t)NN * F_MID * sizeof(float), stream);
    hipMemsetAsync(agg2, 0, (size_t)NN * F_OUT * sizeof(float), stream);

    k_deg_init<<<(NN + 255) / 256, 256, 0, stream>>>(dinv);
    k_deg_count<<<(NE + 255) / 256, 256, 0, stream>>>(ei, dinv);
    k_dinv<<<(NN + 255) / 256, 256, 0, stream>>>(dinv);

    k_gemm1<<<dim3((NN + 63) / 64, F_MID / 64), 256, 0, stream>>>(x, W1, dinv, h1p);
    k_scatter1<<<(NE * 64) / 256, 256, 0, stream>>>(ei, h1p, agg1);
    k_ln1<<<NN, 256, 0, stream>>>(agg1, h1p, dinv, b1, g1, be1);

    k_gemm2<<<(NN + 7) / 8, 320, 0, stream>>>(h1p, W2, dinv, h2p);
    k_scatter2<<<(NE * 64) / 256, 256, 0, stream>>>(ei, h2p, agg2);
    k_final<<<(NN * 64) / 256, 256, 0, stream>>>(agg2, h2p, dinv, b2, g2, be2, out);
}

// Round 2
// 672.854 us; speedup vs baseline: 4.8442x; 4.8442x over previous
//
#include <hip/hip_runtime.h>
#include <math.h>

#define NN 50000
#define NE 800000
#define F_IN 512
#define F_MID 256
#define F_OUT 40
#define LN_EPS 1e-5f

// ---------------- degree count (int) ----------------
__global__ void k_count(const int* __restrict__ ei, int* __restrict__ cnt) {
    int e = blockIdx.x * blockDim.x + threadIdx.x;
    if (e < NE) atomicAdd(&cnt[ei[NE + e]], 1);
}

__global__ void k_dinv(const int* __restrict__ cnt, float* __restrict__ dinv) {
    int i = blockIdx.x * blockDim.x + threadIdx.x;
    if (i < NN) dinv[i] = rsqrtf((float)(cnt[i] + 1));  // +1 self loop
}

// ---------------- single-block exclusive scan -> rowstart[NN+1] ----------------
__global__ __launch_bounds__(1024) void k_scan(const int* __restrict__ cnt, int* __restrict__ rs) {
    __shared__ int wsum[16];
    __shared__ int carry_s;
    int t = threadIdx.x;
    int lane = t & 63, wid = t >> 6;
    if (t == 0) carry_s = 0;
    __syncthreads();
    for (int base = 0; base < NN; base += 1024) {
        int i = base + t;
        int v = (i < NN) ? cnt[i] : 0;
        int s = v;
#pragma unroll
        for (int o = 1; o < 64; o <<= 1) {
            int u = __shfl_up(s, o, 64);
            if (lane >= o) s += u;
        }
        if (lane == 63) wsum[wid] = s;
        __syncthreads();
        if (wid == 0 && lane < 16) {
            int w = wsum[lane];
            int ss = w;
#pragma unroll
            for (int o = 1; o < 16; o <<= 1) {
                int u = __shfl_up(ss, o, 16);
                if (lane >= o) ss += u;
            }
            wsum[lane] = ss - w;  // exclusive wave offset
        }
        __syncthreads();
        int incl = s + wsum[wid] + carry_s;
        if (i < NN) rs[i + 1] = incl;
        __syncthreads();
        if (t == 1023) carry_s = incl;
        __syncthreads();
    }
    if (t == 0) rs[0] = 0;
}

// ---------------- fill CSR: esrc sorted by dst ----------------
__global__ void k_fill(const int* __restrict__ ei, int* __restrict__ cursor,
                       int* __restrict__ esrc) {
    int e = blockIdx.x * blockDim.x + threadIdx.x;
    if (e >= NE) return;
    int src = ei[e];
    int dst = ei[NE + e];
    int pos = atomicAdd(&cursor[dst], 1);
    esrc[pos] = src;
}

// ---------------- GEMM1: h1p = (X @ W1) * dinv[row] ----------------
__global__ __launch_bounds__(256) void k_gemm1(const float* __restrict__ X,
                                               const float* __restrict__ W,
                                               const float* __restrict__ dinv,
                                               float* __restrict__ H) {
    __shared__ float xs[64][33];
    __shared__ float ws[32][64];
    int t = threadIdx.x;
    int r0 = blockIdx.x * 64;
    int c0 = blockIdx.y * 64;
    int n0 = (t & 15) * 4;
    int f0 = (t >> 4) * 4;
    float acc[4][4] = {};

    for (int kk = 0; kk < F_IN; kk += 32) {
        {
            int r = t >> 3;
            int kc = (t & 7) * 4;
#pragma unroll
            for (int h = 0; h < 2; ++h) {
                int row = r + h * 32;
                int gr = r0 + row;
                float4 v = make_float4(0.f, 0.f, 0.f, 0.f);
                if (gr < NN) v = *(const float4*)&X[(size_t)gr * F_IN + kk + kc];
                xs[row][kc + 0] = v.x; xs[row][kc + 1] = v.y;
                xs[row][kc + 2] = v.z; xs[row][kc + 3] = v.w;
            }
        }
        {
#pragma unroll
            for (int h = 0; h < 2; ++h) {
                int i = t + h * 256;
                int k = i >> 4;
                int c = (i & 15) * 4;
                *(float4*)&ws[k][c] = *(const float4*)&W[(size_t)(kk + k) * F_MID + c0 + c];
            }
        }
        __syncthreads();
#pragma unroll
        for (int k = 0; k < 32; ++k) {
            float4 wv = *(float4*)&ws[k][f0];
            float a0 = xs[n0 + 0][k];
            float a1 = xs[n0 + 1][k];
            float a2 = xs[n0 + 2][k];
            float a3 = xs[n0 + 3][k];
            acc[0][0] += a0 * wv.x; acc[0][1] += a0 * wv.y; acc[0][2] += a0 * wv.z; acc[0][3] += a0 * wv.w;
            acc[1][0] += a1 * wv.x; acc[1][1] += a1 * wv.y; acc[1][2] += a1 * wv.z; acc[1][3] += a1 * wv.w;
            acc[2][0] += a2 * wv.x; acc[2][1] += a2 * wv.y; acc[2][2] += a2 * wv.z; acc[2][3] += a2 * wv.w;
            acc[3][0] += a3 * wv.x; acc[3][1] += a3 * wv.y; acc[3][2] += a3 * wv.z; acc[3][3] += a3 * wv.w;
        }
        __syncthreads();
    }
#pragma unroll
    for (int i = 0; i < 4; ++i) {
        int row = r0 + n0 + i;
        if (row >= NN) continue;
        float s = dinv[row];
        float4 o = make_float4(acc[i][0] * s, acc[i][1] * s, acc[i][2] * s, acc[i][3] * s);
        *(float4*)&H[(size_t)row * F_MID + c0 + f0] = o;
    }
}

// ---------------- fused gather-agg + dinv + bias + LN(256) + ELU (wave/node) ----------------
__global__ __launch_bounds__(256) void k_agg1(const int* __restrict__ rs,
                                              const int* __restrict__ esrc,
                                              const float* __restrict__ H,
                                              const float* __restrict__ dinv,
                                              const float* __restrict__ b,
                                              const float* __restrict__ g,
                                              const float* __restrict__ be,
                                              float* __restrict__ O) {
    int node = blockIdx.x * 4 + (threadIdx.x >> 6);
    if (node >= NN) return;
    int lane = threadIdx.x & 63;
    int c = lane * 4;
    float4 acc = *(const float4*)&H[(size_t)node * F_MID + c];  // self (pre-scaled)
    int beg = rs[node], end = rs[node + 1];
    int j = beg;
    for (; j + 1 < end; j += 2) {
        int s0 = esrc[j], s1 = esrc[j + 1];
        float4 v0 = *(const float4*)&H[(size_t)s0 * F_MID + c];
        float4 v1 = *(const float4*)&H[(size_t)s1 * F_MID + c];
        acc.x += v0.x + v1.x; acc.y += v0.y + v1.y;
        acc.z += v0.z + v1.z; acc.w += v0.w + v1.w;
    }
    if (j < end) {
        int s0 = esrc[j];
        float4 v0 = *(const float4*)&H[(size_t)s0 * F_MID + c];
        acc.x += v0.x; acc.y += v0.y; acc.z += v0.z; acc.w += v0.w;
    }
    float s = dinv[node];
    float v0 = s * acc.x + b[c + 0];
    float v1 = s * acc.y + b[c + 1];
    float v2 = s * acc.z + b[c + 2];
    float v3 = s * acc.w + b[c + 3];
    float sum = v0 + v1 + v2 + v3;
    float sq = v0 * v0 + v1 * v1 + v2 * v2 + v3 * v3;
#pragma unroll
    for (int o = 32; o; o >>= 1) {
        sum += __shfl_xor(sum, o, 64);
        sq  += __shfl_xor(sq, o, 64);
    }
    float mu = sum * (1.0f / F_MID);
    float var = sq * (1.0f / F_MID) - mu * mu;
    float rstd = rsqrtf(var + LN_EPS);
    float y0 = (v0 - mu) * rstd * g[c + 0] + be[c + 0];
    float y1 = (v1 - mu) * rstd * g[c + 1] + be[c + 1];
    float y2 = (v2 - mu) * rstd * g[c + 2] + be[c + 2];
    float y3 = (v3 - mu) * rstd * g[c + 3] + be[c + 3];
    float4 o4;
    o4.x = y0 > 0.f ? y0 : expm1f(y0);
    o4.y = y1 > 0.f ? y1 : expm1f(y1);
    o4.z = y2 > 0.f ? y2 : expm1f(y2);
    o4.w = y3 > 0.f ? y3 : expm1f(y3);
    *(float4*)&O[(size_t)node * F_MID + c] = o4;
}

// ---------------- GEMM2: h2p = (h1 @ W2) * dinv  [NN,40] ----------------
__global__ __launch_bounds__(320) void k_gemm2(const float* __restrict__ Hin,
                                               const float* __restrict__ W,
                                               const float* __restrict__ dinv,
                                               float* __restrict__ H2) {
    __shared__ float wls[F_MID * F_OUT];
    __shared__ float as[8][F_MID + 4];
    int t = threadIdx.x;
    int r0 = blockIdx.x * 8;
#pragma unroll
    for (int j = 0; j < 8; ++j) {
        int idx = (t + j * 320) * 4;
        *(float4*)&wls[idx] = *(const float4*)&W[idx];
    }
    for (int j = t; j < 512; j += 320) {
        int n = j >> 6;
        int col = (j & 63) * 4;
        int gr = r0 + n;
        float4 v = make_float4(0.f, 0.f, 0.f, 0.f);
        if (gr < NN) v = *(const float4*)&Hin[(size_t)gr * F_MID + col];
        *(float4*)&as[n][col] = v;
    }
    __syncthreads();
    int n = t / F_OUT;
    int f = t % F_OUT;
    float acc = 0.f;
#pragma unroll 4
    for (int k = 0; k < F_MID; ++k) acc += as[n][k] * wls[k * F_OUT + f];
    int gr = r0 + n;
    if (gr < NN) H2[(size_t)gr * F_OUT + f] = acc * dinv[gr];
}

// ------- fused gather-agg2 + dinv + bias + LN(40) + ELU + log_softmax (wave/node) -------
__global__ __launch_bounds__(256) void k_agg2(const int* __restrict__ rs,
                                              const int* __restrict__ esrc,
                                              const float* __restrict__ H2,
                                              const float* __restrict__ dinv,
                                              const float* __restrict__ b,
                                              const float* __restrict__ g,
                                              const float* __restrict__ be,
                                              float* __restrict__ out) {
    int node = blockIdx.x * 4 + (threadIdx.x >> 6);
    if (node >= NN) return;
    int lane = threadIdx.x & 63;
    bool act = lane < F_OUT;
    size_t off = (size_t)node * F_OUT + lane;
    float acc = act ? H2[off] : 0.f;
    int beg = rs[node], end = rs[node + 1];
    for (int j = beg; j < end; ++j) {
        int src = esrc[j];
        if (act) acc += H2[(size_t)src * F_OUT + lane];
    }
    float v = act ? dinv[node] * acc + b[lane] : 0.f;
    float sum = v;
    float sq = v * v;
#pragma unroll
    for (int o = 32; o; o >>= 1) {
        sum += __shfl_xor(sum, o, 64);
        sq  += __shfl_xor(sq, o, 64);
    }
    float mu = sum * (1.0f / F_OUT);
    float var = sq * (1.0f / F_OUT) - mu * mu;
    float rstd = rsqrtf(var + LN_EPS);
    float y = act ? ((v - mu) * rstd * g[lane] + be[lane]) : 0.f;
    float el = y > 0.f ? y : expm1f(y);
    float m = act ? el : -INFINITY;
#pragma unroll
    for (int o = 32; o; o >>= 1) m = fmaxf(m, __shfl_xor(m, o, 64));
    float ex = act ? expf(el - m) : 0.f;
    float se = ex;
#pragma unroll
    for (int o = 32; o; o >>= 1) se += __shfl_xor(se, o, 64);
    if (act) out[off] = el - m - logf(se);
}

extern "C" void kernel_launch(void* const* d_in, const int* in_sizes, int n_in,
                              void* d_out, int out_size, void* d_ws, size_t ws_size,
                              hipStream_t stream) {
    const float* x   = (const float*)d_in[0];
    const int*   ei  = (const int*)d_in[1];
    const float* W1  = (const float*)d_in[2];
    const float* b1  = (const float*)d_in[3];
    const float* g1  = (const float*)d_in[4];
    const float* be1 = (const float*)d_in[5];
    const float* W2  = (const float*)d_in[6];
    const float* b2  = (const float*)d_in[7];
    const float* g2  = (const float*)d_in[8];
    const float* be2 = (const float*)d_in[9];
    float* out = (float*)d_out;

    float* f = (float*)d_ws;
    float* dinv = f;                               // NN
    float* h1p  = f + 50000;                       // NN*256
    float* h1   = h1p + (size_t)NN * F_MID;        // NN*256
    float* h2p  = h1 + (size_t)NN * F_MID;         // NN*40
    int* ip = (int*)(h2p + (size_t)NN * F_OUT);
    int* cnt      = ip;                            // NN
    int* rowstart = cnt + NN;                      // NN+1
    int* cursor   = rowstart + NN + 1;             // NN
    int* esrc     = cursor + NN;                   // NE

    hipMemsetAsync(cnt, 0, NN * sizeof(int), stream);
    k_count<<<(NE + 255) / 256, 256, 0, stream>>>(ei, cnt);
    k_dinv<<<(NN + 255) / 256, 256, 0, stream>>>(cnt, dinv);
    k_scan<<<1, 1024, 0, stream>>>(cnt, rowstart);
    hipMemcpyAsync(cursor, rowstart, NN * sizeof(int), hipMemcpyDeviceToDevice, stream);
    k_fill<<<(NE + 255) / 256, 256, 0, stream>>>(ei, cursor, esrc);

    k_gemm1<<<dim3((NN + 63) / 64, F_MID / 64), 256, 0, stream>>>(x, W1, dinv, h1p);
    k_agg1<<<(NN + 3) / 4, 256, 0, stream>>>(rowstart, esrc, h1p, dinv, b1, g1, be1, h1);
    k_gemm2<<<(NN + 7) / 8, 320, 0, stream>>>(h1, W2, dinv, h2p);
    k_agg2<<<(NN + 3) / 4, 256, 0, stream>>>(rowstart, esrc, h2p, dinv, b2, g2, be2, out);
}

// Round 3
// 508.637 us; speedup vs baseline: 6.4082x; 1.3229x over previous
//
#include <hip/hip_runtime.h>
#include <math.h>

#define NN 50000
#define NE 800000
#define F_IN 512
#define F_MID 256
#define F_OUT 40
#define LN_EPS 1e-5f

typedef float f32x4 __attribute__((ext_vector_type(4)));
typedef short s16x8 __attribute__((ext_vector_type(8)));

__device__ __forceinline__ short f2bf(float f) {
    unsigned u = __float_as_uint(f);
    return (short)((u + 0x7FFF + ((u >> 16) & 1)) >> 16);  // RNE
}

// ---------------- degree count (int) ----------------
__global__ void k_count(const int* __restrict__ ei, int* __restrict__ cnt) {
    int e = blockIdx.x * blockDim.x + threadIdx.x;
    if (e < NE) atomicAdd(&cnt[ei[NE + e]], 1);
}

__global__ void k_dinv(const int* __restrict__ cnt, float* __restrict__ dinv) {
    int i = blockIdx.x * blockDim.x + threadIdx.x;
    if (i < NN) dinv[i] = rsqrtf((float)(cnt[i] + 1));  // +1 self loop
}

// ---------------- single-block exclusive scan -> rowstart[NN+1] ----------------
__global__ __launch_bounds__(1024) void k_scan(const int* __restrict__ cnt, int* __restrict__ rs) {
    __shared__ int wsum[16];
    __shared__ int carry_s;
    int t = threadIdx.x;
    int lane = t & 63, wid = t >> 6;
    if (t == 0) carry_s = 0;
    __syncthreads();
    for (int base = 0; base < NN; base += 1024) {
        int i = base + t;
        int v = (i < NN) ? cnt[i] : 0;
        int s = v;
#pragma unroll
        for (int o = 1; o < 64; o <<= 1) {
            int u = __shfl_up(s, o, 64);
            if (lane >= o) s += u;
        }
        if (lane == 63) wsum[wid] = s;
        __syncthreads();
        if (wid == 0 && lane < 16) {
            int w = wsum[lane];
            int ss = w;
#pragma unroll
            for (int o = 1; o < 16; o <<= 1) {
                int u = __shfl_up(ss, o, 16);
                if (lane >= o) ss += u;
            }
            wsum[lane] = ss - w;
        }
        __syncthreads();
        int incl = s + wsum[wid] + carry_s;
        if (i < NN) rs[i + 1] = incl;
        __syncthreads();
        if (t == 1023) carry_s = incl;
        __syncthreads();
    }
    if (t == 0) rs[0] = 0;
}

// ---------------- fill CSR: esrc sorted by dst ----------------
__global__ void k_fill(const int* __restrict__ ei, int* __restrict__ cursor,
                       int* __restrict__ esrc) {
    int e = blockIdx.x * blockDim.x + threadIdx.x;
    if (e >= NE) return;
    int src = ei[e];
    int dst = ei[NE + e];
    int pos = atomicAdd(&cursor[dst], 1);
    esrc[pos] = src;
}

// ---------------- W1 [512][256] fp32 -> Wt [256][512] bf16 ----------------
__global__ void k_castW(const float* __restrict__ W, short* __restrict__ Wt) {
    int idx = blockIdx.x * 256 + threadIdx.x;  // out-coalesced order
    int n = idx >> 9, k = idx & 511;
    Wt[idx] = f2bf(W[k * F_MID + n]);
}

// ---------------- GEMM1 (MFMA bf16): h1p = (X @ W1) * dinv[row] ----------------
// BM=64, BN=256 (full), K=512 fully LDS-resident. 256 threads = 4 waves,
// wave w owns cols [w*64, w*64+64). A-tile LDS XOR-swizzled (T2).
__global__ __launch_bounds__(256) void k_gemm1m(const float* __restrict__ X,
                                                const short* __restrict__ Wt,
                                                const float* __restrict__ dinv,
                                                float* __restrict__ H) {
    __shared__ short As[64 * 512];  // 64 KB, [64][512] bf16, swizzled
    int t = threadIdx.x;
    int r0 = blockIdx.x * 64;

    // ---- stage X tile: fp32 -> bf16, swizzle byte ^= (row&7)<<4 ----
    {
        int r = t >> 2;        // 0..63
        int q = t & 3;
        int gr = r0 + r;
        const float* xrow = X + (size_t)gr * F_IN;
        char* lrow = (char*)As + r * 1024;
        unsigned sw = (unsigned)((r & 7) << 4);
#pragma unroll
        for (int j = 0; j < 16; ++j) {
            int chunk = q + j * 4;  // 0..63, 8 floats each
            float4 a = make_float4(0.f, 0.f, 0.f, 0.f);
            float4 b = make_float4(0.f, 0.f, 0.f, 0.f);
            if (gr < NN) {
                a = *(const float4*)&xrow[chunk * 8];
                b = *(const float4*)&xrow[chunk * 8 + 4];
            }
            s16x8 p;
            p[0] = f2bf(a.x); p[1] = f2bf(a.y); p[2] = f2bf(a.z); p[3] = f2bf(a.w);
            p[4] = f2bf(b.x); p[5] = f2bf(b.y); p[6] = f2bf(b.z); p[7] = f2bf(b.w);
            *(s16x8*)(lrow + (((unsigned)(chunk * 16)) ^ sw)) = p;
        }
    }
    __syncthreads();

    int wv = t >> 6;
    int lane = t & 63;
    int n0 = wv * 64;
    int lm = lane & 15;
    int kg = lane >> 4;  // 0..3
    f32x4 acc[4][4];
#pragma unroll
    for (int m = 0; m < 4; ++m)
#pragma unroll
        for (int n = 0; n < 4; ++n) acc[m][n] = (f32x4){0.f, 0.f, 0.f, 0.f};

#pragma unroll
    for (int ks = 0; ks < 16; ++ks) {  // K-step = 32
        s16x8 af[4], bf[4];
#pragma unroll
        for (int m = 0; m < 4; ++m) {
            int rm = m * 16 + lm;
            unsigned byteoff = (unsigned)(rm * 1024) +
                               (((unsigned)(ks * 64 + kg * 16)) ^ ((unsigned)((rm & 7) << 4)));
            af[m] = *(const s16x8*)((const char*)As + byteoff);
        }
#pragma unroll
        for (int n = 0; n < 4; ++n) {
            int rn = n0 + n * 16 + lm;
            bf[n] = *(const s16x8*)&Wt[(size_t)rn * F_IN + ks * 32 + kg * 8];
        }
#pragma unroll
        for (int m = 0; m < 4; ++m)
#pragma unroll
            for (int n = 0; n < 4; ++n)
                acc[m][n] = __builtin_amdgcn_mfma_f32_16x16x32_bf16(af[m], bf[n], acc[m][n], 0, 0, 0);
    }

    // ---- epilogue: D row = m*16 + kg*4 + reg, col = n0 + n*16 + lm ----
#pragma unroll
    for (int m = 0; m < 4; ++m) {
#pragma unroll
        for (int reg = 0; reg < 4; ++reg) {
            int row = r0 + m * 16 + kg * 4 + reg;
            if (row < NN) {
                float s = dinv[row];
#pragma unroll
                for (int n = 0; n < 4; ++n) {
                    H[(size_t)row * F_MID + n0 + n * 16 + lm] = acc[m][n][reg] * s;
                }
            }
        }
    }
}

// ---------------- fused gather-agg + dinv + bias + LN(256) + ELU (wave/node) ----------------
__global__ __launch_bounds__(256) void k_agg1(const int* __restrict__ rs,
                                              const int* __restrict__ esrc,
                                              const float* __restrict__ H,
                                              const float* __restrict__ dinv,
                                              const float* __restrict__ b,
                                              const float* __restrict__ g,
                                              const float* __restrict__ be,
                                              float* __restrict__ O) {
    int node = blockIdx.x * 4 + (threadIdx.x >> 6);
    if (node >= NN) return;
    int lane = threadIdx.x & 63;
    int c = lane * 4;
    float4 acc = *(const float4*)&H[(size_t)node * F_MID + c];  // self (pre-scaled)
    int beg = rs[node], end = rs[node + 1];
    int j = beg;
    for (; j + 1 < end; j += 2) {
        int s0 = esrc[j], s1 = esrc[j + 1];
        float4 v0 = *(const float4*)&H[(size_t)s0 * F_MID + c];
        float4 v1 = *(const float4*)&H[(size_t)s1 * F_MID + c];
        acc.x += v0.x + v1.x; acc.y += v0.y + v1.y;
        acc.z += v0.z + v1.z; acc.w += v0.w + v1.w;
    }
    if (j < end) {
        int s0 = esrc[j];
        float4 v0 = *(const float4*)&H[(size_t)s0 * F_MID + c];
        acc.x += v0.x; acc.y += v0.y; acc.z += v0.z; acc.w += v0.w;
    }
    float s = dinv[node];
    float v0 = s * acc.x + b[c + 0];
    float v1 = s * acc.y + b[c + 1];
    float v2 = s * acc.z + b[c + 2];
    float v3 = s * acc.w + b[c + 3];
    float sum = v0 + v1 + v2 + v3;
    float sq = v0 * v0 + v1 * v1 + v2 * v2 + v3 * v3;
#pragma unroll
    for (int o = 32; o; o >>= 1) {
        sum += __shfl_xor(sum, o, 64);
        sq  += __shfl_xor(sq, o, 64);
    }
    float mu = sum * (1.0f / F_MID);
    float var = sq * (1.0f / F_MID) - mu * mu;
    float rstd = rsqrtf(var + LN_EPS);
    float y0 = (v0 - mu) * rstd * g[c + 0] + be[c + 0];
    float y1 = (v1 - mu) * rstd * g[c + 1] + be[c + 1];
    float y2 = (v2 - mu) * rstd * g[c + 2] + be[c + 2];
    float y3 = (v3 - mu) * rstd * g[c + 3] + be[c + 3];
    float4 o4;
    o4.x = y0 > 0.f ? y0 : expm1f(y0);
    o4.y = y1 > 0.f ? y1 : expm1f(y1);
    o4.z = y2 > 0.f ? y2 : expm1f(y2);
    o4.w = y3 > 0.f ? y3 : expm1f(y3);
    *(float4*)&O[(size_t)node * F_MID + c] = o4;
}

// ---------------- GEMM2: h2p = (h1 @ W2) * dinv  [NN,40] ----------------
__global__ __launch_bounds__(320) void k_gemm2(const float* __restrict__ Hin,
                                               const float* __restrict__ W,
                                               const float* __restrict__ dinv,
                                               float* __restrict__ H2) {
    __shared__ float wls[F_MID * F_OUT];
    __shared__ float as[8][F_MID + 4];
    int t = threadIdx.x;
    int r0 = blockIdx.x * 8;
#pragma unroll
    for (int j = 0; j < 8; ++j) {
        int idx = (t + j * 320) * 4;
        *(float4*)&wls[idx] = *(const float4*)&W[idx];
    }
    for (int j = t; j < 512; j += 320) {
        int n = j >> 6;
        int col = (j & 63) * 4;
        int gr = r0 + n;
        float4 v = make_float4(0.f, 0.f, 0.f, 0.f);
        if (gr < NN) v = *(const float4*)&Hin[(size_t)gr * F_MID + col];
        *(float4*)&as[n][col] = v;
    }
    __syncthreads();
    int n = t / F_OUT;
    int f = t % F_OUT;
    float acc = 0.f;
#pragma unroll 4
    for (int k = 0; k < F_MID; ++k) acc += as[n][k] * wls[k * F_OUT + f];
    int gr = r0 + n;
    if (gr < NN) H2[(size_t)gr * F_OUT + f] = acc * dinv[gr];
}

// ------- fused gather-agg2 + dinv + bias + LN(40) + ELU + log_softmax (wave/node) -------
__global__ __launch_bounds__(256) void k_agg2(const int* __restrict__ rs,
                                              const int* __restrict__ esrc,
                                              const float* __restrict__ H2,
                                              const float* __restrict__ dinv,
                                              const float* __restrict__ b,
                                              const float* __restrict__ g,
                                              const float* __restrict__ be,
                                              float* __restrict__ out) {
    int node = blockIdx.x * 4 + (threadIdx.x >> 6);
    if (node >= NN) return;
    int lane = threadIdx.x & 63;
    bool act = lane < F_OUT;
    size_t off = (size_t)node * F_OUT + lane;
    float acc = act ? H2[off] : 0.f;
    int beg = rs[node], end = rs[node + 1];
    for (int j = beg; j < end; ++j) {
        int src = esrc[j];
        if (act) acc += H2[(size_t)src * F_OUT + lane];
    }
    float v = act ? dinv[node] * acc + b[lane] : 0.f;
    float sum = v;
    float sq = v * v;
#pragma unroll
    for (int o = 32; o; o >>= 1) {
        sum += __shfl_xor(sum, o, 64);
        sq  += __shfl_xor(sq, o, 64);
    }
    float mu = sum * (1.0f / F_OUT);
    float var = sq * (1.0f / F_OUT) - mu * mu;
    float rstd = rsqrtf(var + LN_EPS);
    float y = act ? ((v - mu) * rstd * g[lane] + be[lane]) : 0.f;
    float el = y > 0.f ? y : expm1f(y);
    float m = act ? el : -INFINITY;
#pragma unroll
    for (int o = 32; o; o >>= 1) m = fmaxf(m, __shfl_xor(m, o, 64));
    float ex = act ? expf(el - m) : 0.f;
    float se = ex;
#pragma unroll
    for (int o = 32; o; o >>= 1) se += __shfl_xor(se, o, 64);
    if (act) out[off] = el - m - logf(se);
}

extern "C" void kernel_launch(void* const* d_in, const int* in_sizes, int n_in,
                              void* d_out, int out_size, void* d_ws, size_t ws_size,
                              hipStream_t stream) {
    const float* x   = (const float*)d_in[0];
    const int*   ei  = (const int*)d_in[1];
    const float* W1  = (const float*)d_in[2];
    const float* b1  = (const float*)d_in[3];
    const float* g1  = (const float*)d_in[4];
    const float* be1 = (const float*)d_in[5];
    const float* W2  = (const float*)d_in[6];
    const float* b2  = (const float*)d_in[7];
    const float* g2  = (const float*)d_in[8];
    const float* be2 = (const float*)d_in[9];
    float* out = (float*)d_out;

    float* f = (float*)d_ws;
    float* dinv = f;                               // NN floats (200000 B, 16B-mult)
    float* h1p  = f + 50000;                       // NN*256
    float* h1   = h1p + (size_t)NN * F_MID;        // NN*256
    float* h2p  = h1 + (size_t)NN * F_MID;         // NN*40 (8MB, 16B-mult)
    short* Wt   = (short*)(h2p + (size_t)NN * F_OUT);  // 256*512 bf16 (16B aligned)
    int* ip = (int*)(Wt + F_MID * F_IN);
    int* cnt      = ip;                            // NN
    int* rowstart = cnt + NN;                      // NN+1
    int* cursor   = rowstart + NN + 1;             // NN
    int* esrc     = cursor + NN;                   // NE

    hipMemsetAsync(cnt, 0, NN * sizeof(int), stream);
    k_count<<<(NE + 255) / 256, 256, 0, stream>>>(ei, cnt);
    k_dinv<<<(NN + 255) / 256, 256, 0, stream>>>(cnt, dinv);
    k_scan<<<1, 1024, 0, stream>>>(cnt, rowstart);
    hipMemcpyAsync(cursor, rowstart, NN * sizeof(int), hipMemcpyDeviceToDevice, stream);
    k_fill<<<(NE + 255) / 256, 256, 0, stream>>>(ei, cursor, esrc);
    k_castW<<<512, 256, 0, stream>>>(W1, Wt);

    k_gemm1m<<<(NN + 63) / 64, 256, 0, stream>>>(x, Wt, dinv, h1p);
    k_agg1<<<(NN + 3) / 4, 256, 0, stream>>>(rowstart, esrc, h1p, dinv, b1, g1, be1, h1);
    k_gemm2<<<(NN + 7) / 8, 320, 0, stream>>>(h1, W2, dinv, h2p);
    k_agg2<<<(NN + 3) / 4, 256, 0, stream>>>(rowstart, esrc, h2p, dinv, b2, g2, be2, out);
}

// Round 4
// 301.833 us; speedup vs baseline: 10.7989x; 1.6852x over previous
//
#include <hip/hip_runtime.h>
#include <math.h>

#define NN 50000
#define NE 800000
#define F_IN 512
#define F_MID 256
#define F_OUT 40
#define LN_EPS 1e-5f

typedef float f32x4 __attribute__((ext_vector_type(4)));
typedef short s16x8 __attribute__((ext_vector_type(8)));
typedef unsigned short ushort;

__device__ __forceinline__ short f2bf(float f) {
    unsigned u = __float_as_uint(f);
    return (short)((u + 0x7FFF + ((u >> 16) & 1)) >> 16);  // RNE
}
__device__ __forceinline__ float bf2f(ushort u) {
    return __uint_as_float(((unsigned)u) << 16);
}

// ---------------- degree count (int) ----------------
__global__ void k_count(const int* __restrict__ ei, int* __restrict__ cnt) {
    int e = blockIdx.x * blockDim.x + threadIdx.x;
    if (e < NE) atomicAdd(&cnt[ei[NE + e]], 1);
}

__global__ void k_dinv(const int* __restrict__ cnt, float* __restrict__ dinv) {
    int i = blockIdx.x * blockDim.x + threadIdx.x;
    if (i < NN) dinv[i] = rsqrtf((float)(cnt[i] + 1));  // +1 self loop
}

// ---------------- hierarchical scan: rowstart[NN+1] ----------------
__global__ __launch_bounds__(1024) void k_scan1(const int* __restrict__ cnt,
                                                int* __restrict__ rs,
                                                int* __restrict__ bsum) {
    __shared__ int wsum[16];
    int t = threadIdx.x;
    int lane = t & 63, wid = t >> 6;
    int i = blockIdx.x * 1024 + t;
    int v = (i < NN) ? cnt[i] : 0;
    int s = v;
#pragma unroll
    for (int o = 1; o < 64; o <<= 1) {
        int u = __shfl_up(s, o, 64);
        if (lane >= o) s += u;
    }
    if (lane == 63) wsum[wid] = s;
    __syncthreads();
    if (wid == 0 && lane < 16) {
        int w = wsum[lane];
        int ss = w;
#pragma unroll
        for (int o = 1; o < 16; o <<= 1) {
            int u = __shfl_up(ss, o, 16);
            if (lane >= o) ss += u;
        }
        wsum[lane] = ss - w;
    }
    __syncthreads();
    int incl = s + wsum[wid];
    if (i < NN) rs[i + 1] = incl;
    if (t == 1023) bsum[blockIdx.x] = incl;
}

__global__ void k_scan2(int* __restrict__ bsum, int* __restrict__ boff, int nb) {
    int t = threadIdx.x;  // 64 threads
    int v = (t < nb) ? bsum[t] : 0;
    int s = v;
#pragma unroll
    for (int o = 1; o < 64; o <<= 1) {
        int u = __shfl_up(s, o, 64);
        if (t >= o) s += u;
    }
    if (t < nb) boff[t] = s - v;  // exclusive
}

__global__ __launch_bounds__(1024) void k_scan3(int* __restrict__ rs,
                                                const int* __restrict__ boff,
                                                int* __restrict__ cursor) {
    int i = blockIdx.x * 1024 + threadIdx.x;
    if (i == 0) { rs[0] = 0; cursor[0] = 0; }
    if (i < NN) {
        int v = rs[i + 1] + boff[blockIdx.x];
        rs[i + 1] = v;
        if (i + 1 < NN) cursor[i + 1] = v;
    }
}

// ---------------- fill CSR: esrc sorted by dst ----------------
__global__ void k_fill(const int* __restrict__ ei, int* __restrict__ cursor,
                       int* __restrict__ esrc) {
    int e = blockIdx.x * blockDim.x + threadIdx.x;
    if (e >= NE) return;
    int src = ei[e];
    int dst = ei[NE + e];
    int pos = atomicAdd(&cursor[dst], 1);
    esrc[pos] = src;
}

// ---------------- W1 [512][256] fp32 -> Wt [256][512] bf16 ----------------
__global__ void k_castW(const float* __restrict__ W, short* __restrict__ Wt) {
    int idx = blockIdx.x * 256 + threadIdx.x;
    int n = idx >> 9, k = idx & 511;
    Wt[idx] = f2bf(W[k * F_MID + n]);
}

// ---------------- W2 [256][40] fp32 -> W2t [48][256] bf16 (padded) ----------------
__global__ void k_castW2(const float* __restrict__ W, short* __restrict__ Wt) {
    int n = blockIdx.x;          // 0..47
    int k = threadIdx.x;         // 0..255
    Wt[n * 256 + k] = (n < F_OUT) ? f2bf(W[k * F_OUT + n]) : (short)0;
}

// ---------------- GEMM1 (MFMA bf16): h1p = bf16((X @ W1) * dinv[row]) ----------------
__global__ __launch_bounds__(256) void k_gemm1m(const float* __restrict__ X,
                                                const short* __restrict__ Wt,
                                                const float* __restrict__ dinv,
                                                ushort* __restrict__ H) {
    __shared__ short As[64 * 512];  // 64 KB, swizzled
    int t = threadIdx.x;
    int r0 = blockIdx.x * 64;

    {
        int r = t >> 2;
        int q = t & 3;
        int gr = r0 + r;
        const float* xrow = X + (size_t)gr * F_IN;
        char* lrow = (char*)As + r * 1024;
        unsigned sw = (unsigned)((r & 7) << 4);
#pragma unroll
        for (int j = 0; j < 16; ++j) {
            int chunk = q + j * 4;
            float4 a = make_float4(0.f, 0.f, 0.f, 0.f);
            float4 b = make_float4(0.f, 0.f, 0.f, 0.f);
            if (gr < NN) {
                a = *(const float4*)&xrow[chunk * 8];
                b = *(const float4*)&xrow[chunk * 8 + 4];
            }
            s16x8 p;
            p[0] = f2bf(a.x); p[1] = f2bf(a.y); p[2] = f2bf(a.z); p[3] = f2bf(a.w);
            p[4] = f2bf(b.x); p[5] = f2bf(b.y); p[6] = f2bf(b.z); p[7] = f2bf(b.w);
            *(s16x8*)(lrow + (((unsigned)(chunk * 16)) ^ sw)) = p;
        }
    }
    __syncthreads();

    int wv = t >> 6;
    int lane = t & 63;
    int n0 = wv * 64;
    int lm = lane & 15;
    int kg = lane >> 4;
    f32x4 acc[4][4];
#pragma unroll
    for (int m = 0; m < 4; ++m)
#pragma unroll
        for (int n = 0; n < 4; ++n) acc[m][n] = (f32x4){0.f, 0.f, 0.f, 0.f};

#pragma unroll
    for (int ks = 0; ks < 16; ++ks) {
        s16x8 af[4], bf[4];
#pragma unroll
        for (int m = 0; m < 4; ++m) {
            int rm = m * 16 + lm;
            unsigned byteoff = (unsigned)(rm * 1024) +
                               (((unsigned)(ks * 64 + kg * 16)) ^ ((unsigned)((rm & 7) << 4)));
            af[m] = *(const s16x8*)((const char*)As + byteoff);
        }
#pragma unroll
        for (int n = 0; n < 4; ++n) {
            int rn = n0 + n * 16 + lm;
            bf[n] = *(const s16x8*)&Wt[(size_t)rn * F_IN + ks * 32 + kg * 8];
        }
#pragma unroll
        for (int m = 0; m < 4; ++m)
#pragma unroll
            for (int n = 0; n < 4; ++n)
                acc[m][n] = __builtin_amdgcn_mfma_f32_16x16x32_bf16(af[m], bf[n], acc[m][n], 0, 0, 0);
    }

#pragma unroll
    for (int m = 0; m < 4; ++m) {
#pragma unroll
        for (int reg = 0; reg < 4; ++reg) {
            int row = r0 + m * 16 + kg * 4 + reg;
            if (row < NN) {
                float s = dinv[row];
#pragma unroll
                for (int n = 0; n < 4; ++n) {
                    H[(size_t)row * F_MID + n0 + n * 16 + lm] = (ushort)f2bf(acc[m][n][reg] * s);
                }
            }
        }
    }
}

// ---------------- fused gather-agg + dinv + bias + LN(256) + ELU -> bf16 ----------------
__global__ __launch_bounds__(256) void k_agg1(const int* __restrict__ rs,
                                              const int* __restrict__ esrc,
                                              const ushort* __restrict__ H,
                                              const float* __restrict__ dinv,
                                              const float* __restrict__ b,
                                              const float* __restrict__ g,
                                              const float* __restrict__ be,
                                              ushort* __restrict__ O) {
    int node = blockIdx.x * 4 + (threadIdx.x >> 6);
    if (node >= NN) return;
    int lane = threadIdx.x & 63;
    int c = lane * 4;
    ushort4 sv = *(const ushort4*)&H[(size_t)node * F_MID + c];
    float a0 = bf2f(sv.x), a1 = bf2f(sv.y), a2 = bf2f(sv.z), a3 = bf2f(sv.w);
    int beg = rs[node], end = rs[node + 1];
    int j = beg;
    for (; j + 3 < end; j += 4) {
        int s0 = esrc[j], s1 = esrc[j + 1], s2 = esrc[j + 2], s3 = esrc[j + 3];
        ushort4 v0 = *(const ushort4*)&H[(size_t)s0 * F_MID + c];
        ushort4 v1 = *(const ushort4*)&H[(size_t)s1 * F_MID + c];
        ushort4 v2 = *(const ushort4*)&H[(size_t)s2 * F_MID + c];
        ushort4 v3 = *(const ushort4*)&H[(size_t)s3 * F_MID + c];
        a0 += bf2f(v0.x) + bf2f(v1.x) + bf2f(v2.x) + bf2f(v3.x);
        a1 += bf2f(v0.y) + bf2f(v1.y) + bf2f(v2.y) + bf2f(v3.y);
        a2 += bf2f(v0.z) + bf2f(v1.z) + bf2f(v2.z) + bf2f(v3.z);
        a3 += bf2f(v0.w) + bf2f(v1.w) + bf2f(v2.w) + bf2f(v3.w);
    }
    for (; j < end; ++j) {
        int s0 = esrc[j];
        ushort4 v0 = *(const ushort4*)&H[(size_t)s0 * F_MID + c];
        a0 += bf2f(v0.x); a1 += bf2f(v0.y); a2 += bf2f(v0.z); a3 += bf2f(v0.w);
    }
    float s = dinv[node];
    float v0 = s * a0 + b[c + 0];
    float v1 = s * a1 + b[c + 1];
    float v2 = s * a2 + b[c + 2];
    float v3 = s * a3 + b[c + 3];
    float sum = v0 + v1 + v2 + v3;
    float sq = v0 * v0 + v1 * v1 + v2 * v2 + v3 * v3;
#pragma unroll
    for (int o = 32; o; o >>= 1) {
        sum += __shfl_xor(sum, o, 64);
        sq  += __shfl_xor(sq, o, 64);
    }
    float mu = sum * (1.0f / F_MID);
    float var = sq * (1.0f / F_MID) - mu * mu;
    float rstd = rsqrtf(var + LN_EPS);
    float y0 = (v0 - mu) * rstd * g[c + 0] + be[c + 0];
    float y1 = (v1 - mu) * rstd * g[c + 1] + be[c + 1];
    float y2 = (v2 - mu) * rstd * g[c + 2] + be[c + 2];
    float y3 = (v3 - mu) * rstd * g[c + 3] + be[c + 3];
    ushort4 o4;
    o4.x = (ushort)f2bf(y0 > 0.f ? y0 : expm1f(y0));
    o4.y = (ushort)f2bf(y1 > 0.f ? y1 : expm1f(y1));
    o4.z = (ushort)f2bf(y2 > 0.f ? y2 : expm1f(y2));
    o4.w = (ushort)f2bf(y3 > 0.f ? y3 : expm1f(y3));
    *(ushort4*)&O[(size_t)node * F_MID + c] = o4;
}

// ---------------- GEMM2 (MFMA bf16): h2p = bf16((h1 @ W2) * dinv) [NN,40] ----------------
__global__ __launch_bounds__(256) void k_gemm2m(const ushort* __restrict__ Hin,
                                                const short* __restrict__ W2t,
                                                const float* __restrict__ dinv,
                                                ushort* __restrict__ H2) {
    __shared__ short As[64 * 256];  // 32 KB, swizzled (512B rows)
    int t = threadIdx.x;
    int r0 = blockIdx.x * 64;

    {
        int r = t >> 2;
        int q = t & 3;
        int gr = r0 + r;
        char* lrow = (char*)As + r * 512;
        unsigned sw = (unsigned)((r & 7) << 4);
#pragma unroll
        for (int j = 0; j < 8; ++j) {
            int chunk = q + j * 4;  // 0..31, 16B each
            s16x8 p = (s16x8)0;
            if (gr < NN) p = *(const s16x8*)&Hin[(size_t)gr * F_MID + chunk * 8];
            *(s16x8*)(lrow + (((unsigned)(chunk * 16)) ^ sw)) = p;
        }
    }
    __syncthreads();

    int wv = t >> 6;
    int lane = t & 63;
    int lm = lane & 15;
    int kg = lane >> 4;
    f32x4 acc[3];
#pragma unroll
    for (int n = 0; n < 3; ++n) acc[n] = (f32x4){0.f, 0.f, 0.f, 0.f};

#pragma unroll
    for (int ks = 0; ks < 8; ++ks) {
        int rm = wv * 16 + lm;
        unsigned byteoff = (unsigned)(rm * 512) +
                           (((unsigned)(ks * 64 + kg * 16)) ^ ((unsigned)((rm & 7) << 4)));
        s16x8 af = *(const s16x8*)((const char*)As + byteoff);
#pragma unroll
        for (int n = 0; n < 3; ++n) {
            int rn = n * 16 + lm;
            s16x8 bf = *(const s16x8*)&W2t[rn * F_MID + ks * 32 + kg * 8];
            acc[n] = __builtin_amdgcn_mfma_f32_16x16x32_bf16(af, bf, acc[n], 0, 0, 0);
        }
    }

#pragma unroll
    for (int n = 0; n < 3; ++n) {
        int col = n * 16 + lm;
        if (col >= F_OUT) continue;
#pragma unroll
        for (int reg = 0; reg < 4; ++reg) {
            int row = r0 + wv * 16 + kg * 4 + reg;
            if (row < NN) {
                H2[(size_t)row * F_OUT + col] = (ushort)f2bf(acc[n][reg] * dinv[row]);
            }
        }
    }
}

// ------- fused gather-agg2 + dinv + bias + LN(40) + ELU + log_softmax -------
__global__ __launch_bounds__(256) void k_agg2(const int* __restrict__ rs,
                                              const int* __restrict__ esrc,
                                              const ushort* __restrict__ H2,
                                              const float* __restrict__ dinv,
                                              const float* __restrict__ b,
                                              const float* __restrict__ g,
                                              const float* __restrict__ be,
                                              float* __restrict__ out) {
    int node = blockIdx.x * 4 + (threadIdx.x >> 6);
    if (node >= NN) return;
    int lane = threadIdx.x & 63;
    bool act = lane < F_OUT;
    size_t off = (size_t)node * F_OUT + lane;
    float acc = act ? bf2f(H2[off]) : 0.f;
    int beg = rs[node], end = rs[node + 1];
    int j = beg;
    for (; j + 1 < end; j += 2) {
        int s0 = esrc[j], s1 = esrc[j + 1];
        if (act) {
            acc += bf2f(H2[(size_t)s0 * F_OUT + lane]);
            acc += bf2f(H2[(size_t)s1 * F_OUT + lane]);
        }
    }
    if (j < end) {
        int s0 = esrc[j];
        if (act) acc += bf2f(H2[(size_t)s0 * F_OUT + lane]);
    }
    float v = act ? dinv[node] * acc + b[lane] : 0.f;
    float sum = v;
    float sq = v * v;
#pragma unroll
    for (int o = 32; o; o >>= 1) {
        sum += __shfl_xor(sum, o, 64);
        sq  += __shfl_xor(sq, o, 64);
    }
    float mu = sum * (1.0f / F_OUT);
    float var = sq * (1.0f / F_OUT) - mu * mu;
    float rstd = rsqrtf(var + LN_EPS);
    float y = act ? ((v - mu) * rstd * g[lane] + be[lane]) : 0.f;
    float el = y > 0.f ? y : expm1f(y);
    float m = act ? el : -INFINITY;
#pragma unroll
    for (int o = 32; o; o >>= 1) m = fmaxf(m, __shfl_xor(m, o, 64));
    float ex = act ? expf(el - m) : 0.f;
    float se = ex;
#pragma unroll
    for (int o = 32; o; o >>= 1) se += __shfl_xor(se, o, 64);
    if (act) out[off] = el - m - logf(se);
}

extern "C" void kernel_launch(void* const* d_in, const int* in_sizes, int n_in,
                              void* d_out, int out_size, void* d_ws, size_t ws_size,
                              hipStream_t stream) {
    const float* x   = (const float*)d_in[0];
    const int*   ei  = (const int*)d_in[1];
    const float* W1  = (const float*)d_in[2];
    const float* b1  = (const float*)d_in[3];
    const float* g1  = (const float*)d_in[4];
    const float* be1 = (const float*)d_in[5];
    const float* W2  = (const float*)d_in[6];
    const float* b2  = (const float*)d_in[7];
    const float* g2  = (const float*)d_in[8];
    const float* be2 = (const float*)d_in[9];
    float* out = (float*)d_out;

    char* p = (char*)d_ws;
    float* dinv = (float*)p;            p += 50000 * 4;          // 200000 B (16-mult)
    ushort* h1p = (ushort*)p;           p += (size_t)NN * F_MID * 2;
    ushort* h1  = (ushort*)p;           p += (size_t)NN * F_MID * 2;
    ushort* h2p = (ushort*)p;           p += (size_t)NN * F_OUT * 2;
    short* Wt   = (short*)p;            p += (size_t)F_MID * F_IN * 2;
    short* W2t  = (short*)p;            p += 48 * 256 * 2;
    int* cnt      = (int*)p;            p += NN * 4;
    int* rowstart = (int*)p;            p += (NN + 1) * 4;
    int* cursor   = (int*)p;            p += NN * 4;
    int* bsum     = (int*)p;            p += 64 * 4;
    int* boff     = (int*)p;            p += 64 * 4;
    int* esrc     = (int*)p;

    const int NB = (NN + 1023) / 1024;  // 49

    hipMemsetAsync(cnt, 0, NN * sizeof(int), stream);
    k_count<<<(NE + 255) / 256, 256, 0, stream>>>(ei, cnt);
    k_dinv<<<(NN + 255) / 256, 256, 0, stream>>>(cnt, dinv);
    k_scan1<<<NB, 1024, 0, stream>>>(cnt, rowstart, bsum);
    k_scan2<<<1, 64, 0, stream>>>(bsum, boff, NB);
    k_scan3<<<NB, 1024, 0, stream>>>(rowstart, boff, cursor);
    k_fill<<<(NE + 255) / 256, 256, 0, stream>>>(ei, cursor, esrc);
    k_castW<<<512, 256, 0, stream>>>(W1, Wt);
    k_castW2<<<48, 256, 0, stream>>>(W2, W2t);

    k_gemm1m<<<(NN + 63) / 64, 256, 0, stream>>>(x, Wt, dinv, h1p);
    k_agg1<<<(NN + 3) / 4, 256, 0, stream>>>(rowstart, esrc, h1p, dinv, b1, g1, be1, h1);
    k_gemm2m<<<(NN + 63) / 64, 256, 0, stream>>>(h1, W2t, dinv, h2p);
    k_agg2<<<(NN + 3) / 4, 256, 0, stream>>>(rowstart, esrc, h2p, dinv, b2, g2, be2, out);
}